// Round 1
// baseline (5862.867 us; speedup 1.0000x reference)
//
#include <hip/hip_runtime.h>
#include <hip/hip_bf16.h>

// Problem constants (B=1)
#define TT 2048   // tokens = B*S
#define DD 2048   // hidden dim
#define NHQ 16    // query heads
#define KVH 4     // kv heads
#define HDIM 128  // head dim
#define NE 8      // experts
#define FF 2048   // ffn dim
#define SCALING 0.08838834764831845f  // 1/sqrt(128)
#define RMS_EPS 1e-5f
#define L2_EPS 1e-6f

#define TILE 64
#define BKK 16

// ---------------------------------------------------------------- rmsnorm
__global__ __launch_bounds__(256) void rmsnorm_kernel(
    const float* __restrict__ x, const float* __restrict__ w,
    float* __restrict__ y)
{
    const int tok = blockIdx.x;
    const float* xr = x + (size_t)tok * DD;
    float4 v[2];
    float ss = 0.0f;
#pragma unroll
    for (int i = 0; i < 2; ++i) {
        int d4 = threadIdx.x + i * 256;
        v[i] = *(const float4*)&xr[d4 * 4];
        ss += v[i].x * v[i].x + v[i].y * v[i].y + v[i].z * v[i].z + v[i].w * v[i].w;
    }
    for (int off = 32; off; off >>= 1) ss += __shfl_xor(ss, off);
    __shared__ float red[4];
    const int wid = threadIdx.x >> 6, lane = threadIdx.x & 63;
    if (lane == 0) red[wid] = ss;
    __syncthreads();
    const float tot = red[0] + red[1] + red[2] + red[3];
    const float rs = rsqrtf(tot * (1.0f / DD) + RMS_EPS);
    float* yr = y + (size_t)tok * DD;
#pragma unroll
    for (int i = 0; i < 2; ++i) {
        int d = (threadIdx.x + i * 256) * 4;
        float4 wv = *(const float4*)&w[d];
        float4 o;
        o.x = v[i].x * rs * wv.x;
        o.y = v[i].y * rs * wv.y;
        o.z = v[i].z * rs * wv.z;
        o.w = v[i].w * rs * wv.w;
        *(float4*)&yr[d] = o;
    }
}

// ---------------------------------------------------------------- fp32 tiled GEMM
// C[M,N] = A[M,K] @ B[K,N]  (+ addsrc) ; M,N multiples of 64, K multiple of 16
__global__ __launch_bounds__(256) void gemm_f32_kernel(
    const float* __restrict__ A, const float* __restrict__ B,
    float* __restrict__ C, const float* __restrict__ addsrc,
    int M, int N, int K)
{
    __shared__ alignas(16) float As[BKK][TILE];   // [k][m]
    __shared__ alignas(16) float Bs[BKK][TILE];   // [k][n]
    const int tid = threadIdx.x;
    const int tx = tid & 15, ty = tid >> 4;
    const int row0 = blockIdx.y * TILE, col0 = blockIdx.x * TILE;
    const int am = tid >> 2, ak = (tid & 3) << 2;
    const int bk = tid >> 4, bn = (tid & 15) << 2;
    const float* Aptr = A + (size_t)(row0 + am) * K + ak;
    const float* Bptr = B + (size_t)bk * N + col0 + bn;
    float acc[4][4] = {};
    for (int k0 = 0; k0 < K; k0 += BKK) {
        float4 av = *(const float4*)(Aptr + k0);
        float4 bv = *(const float4*)(Bptr + (size_t)k0 * N);
        __syncthreads();
        As[ak + 0][am] = av.x;
        As[ak + 1][am] = av.y;
        As[ak + 2][am] = av.z;
        As[ak + 3][am] = av.w;
        *(float4*)&Bs[bk][bn] = bv;
        __syncthreads();
#pragma unroll
        for (int kk = 0; kk < BKK; ++kk) {
            const float4 a = *(const float4*)&As[kk][ty << 2];
            const float4 b = *(const float4*)&Bs[kk][tx << 2];
            const float ar[4] = {a.x, a.y, a.z, a.w};
            const float br[4] = {b.x, b.y, b.z, b.w};
#pragma unroll
            for (int i = 0; i < 4; ++i)
#pragma unroll
                for (int j = 0; j < 4; ++j)
                    acc[i][j] = fmaf(ar[i], br[j], acc[i][j]);
        }
    }
#pragma unroll
    for (int i = 0; i < 4; ++i) {
        const size_t idx = (size_t)(row0 + (ty << 2) + i) * N + col0 + (tx << 2);
        float4 o = make_float4(acc[i][0], acc[i][1], acc[i][2], acc[i][3]);
        if (addsrc) {
            float4 r = *(const float4*)&addsrc[idx];
            o.x += r.x; o.y += r.y; o.z += r.z; o.w += r.w;
        }
        *(float4*)&C[idx] = o;
    }
}

// ---------------------------------------------------------------- RoPE + l2norm (in place)
// x: (TT*nh, HDIM) rows; one wave per row
__global__ __launch_bounds__(256) void rope_l2_kernel(
    float* __restrict__ x, int nh,
    const float* __restrict__ cosb, const float* __restrict__ sinb)
{
    const int wid = threadIdx.x >> 6, lane = threadIdx.x & 63;
    const int row = blockIdx.x * 4 + wid;
    const int tok = row / nh;
    float* xr = x + (size_t)row * HDIM;
    float2 ab = *(const float2*)&xr[lane * 2];
    const float c = cosb[tok * (HDIM / 2) + lane];
    const float s = sinb[tok * (HDIM / 2) + lane];
    const float o0 = ab.x * c - ab.y * s;
    const float o1 = ab.x * s + ab.y * c;
    float ss = o0 * o0 + o1 * o1;
    for (int off = 32; off; off >>= 1) ss += __shfl_xor(ss, off);
    const float r = rsqrtf(ss * (1.0f / HDIM) + L2_EPS);
    *(float2*)&xr[lane * 2] = make_float2(o0 * r, o1 * r);
}

// ---------------------------------------------------------------- causal attention
// q: (TT, NHQ, HDIM), k/v: (TT, KVH, HDIM), o: (TT, NHQ, HDIM). One wave per q row.
__global__ __launch_bounds__(256) void attention_kernel(
    const float* __restrict__ q, const float* __restrict__ k,
    const float* __restrict__ v, float* __restrict__ o)
{
    __shared__ float sc[4][TT];     // 32 KB score rows (one per wave)
    __shared__ float qs[4][HDIM];   // 2 KB
    const int wid = threadIdx.x >> 6, lane = threadIdx.x & 63;
    const int r = blockIdx.x * 4 + wid;
    const int h = blockIdx.y;
    const int kvh = h >> 2;   // NHQ/KVH = 4
    float2 qv = *(const float2*)&q[((size_t)r * NHQ + h) * HDIM + lane * 2];
    qs[wid][lane * 2] = qv.x;
    qs[wid][lane * 2 + 1] = qv.y;
    __syncthreads();
    // phase 1: scores (strictly causal; masked entries never computed == exp->0)
    float mx = -1e30f;
    for (int j = lane; j <= r; j += 64) {
        const float* kr = &k[((size_t)j * KVH + kvh) * HDIM];
        float acc = 0.0f;
#pragma unroll
        for (int d = 0; d < HDIM; d += 4) {
            float4 kv4 = *(const float4*)&kr[d];
            acc += qs[wid][d] * kv4.x + qs[wid][d + 1] * kv4.y +
                   qs[wid][d + 2] * kv4.z + qs[wid][d + 3] * kv4.w;
        }
        acc *= SCALING;
        sc[wid][j] = acc;
        mx = fmaxf(mx, acc);
    }
    for (int off = 32; off; off >>= 1) mx = fmaxf(mx, __shfl_xor(mx, off));
    // phase 2: exp + sum (each lane touches only its own j's)
    float sum = 0.0f;
    for (int j = lane; j <= r; j += 64) {
        float e = __expf(sc[wid][j] - mx);
        sc[wid][j] = e;
        sum += e;
    }
    for (int off = 32; off; off >>= 1) sum += __shfl_xor(sum, off);
    const float inv = 1.0f / sum;
    __syncthreads();   // make every lane's sc[] writes visible for phase 3
    // phase 3: PV, lane covers 2 dims (coalesced V reads)
    const int d0 = lane * 2;
    float a0 = 0.0f, a1 = 0.0f;
    for (int j = 0; j <= r; ++j) {
        const float p = sc[wid][j];
        float2 vv = *(const float2*)&v[((size_t)j * KVH + kvh) * HDIM + d0];
        a0 = fmaf(p, vv.x, a0);
        a1 = fmaf(p, vv.y, a1);
    }
    *(float2*)&o[((size_t)r * NHQ + h) * HDIM + d0] = make_float2(a0 * inv, a1 * inv);
}

// ---------------------------------------------------------------- router (top-1 + sigmoid gate)
__global__ __launch_bounds__(256) void router_kernel(
    const float* __restrict__ t, const float* __restrict__ rw,
    int* __restrict__ topi, float* __restrict__ gate)
{
    const int wid = threadIdx.x >> 6, lane = threadIdx.x & 63;
    const int tok = blockIdx.x * 4 + wid;
    const float* x = t + (size_t)tok * DD;
    float acc[NE] = {};
    for (int d = lane; d < DD; d += 64) {
        const float xv = x[d];
        const float4 r0 = *(const float4*)&rw[d * NE];
        const float4 r1 = *(const float4*)&rw[d * NE + 4];
        acc[0] = fmaf(xv, r0.x, acc[0]); acc[1] = fmaf(xv, r0.y, acc[1]);
        acc[2] = fmaf(xv, r0.z, acc[2]); acc[3] = fmaf(xv, r0.w, acc[3]);
        acc[4] = fmaf(xv, r1.x, acc[4]); acc[5] = fmaf(xv, r1.y, acc[5]);
        acc[6] = fmaf(xv, r1.z, acc[6]); acc[7] = fmaf(xv, r1.w, acc[7]);
    }
#pragma unroll
    for (int e = 0; e < NE; ++e)
        for (int off = 32; off; off >>= 1) acc[e] += __shfl_xor(acc[e], off);
    if (lane == 0) {
        int best = 0;
        float bv = acc[0];
#pragma unroll
        for (int e = 1; e < NE; ++e)
            if (acc[e] > bv) { bv = acc[e]; best = e; }
        topi[tok] = best;
        gate[tok] = 1.0f / (1.0f + __expf(-bv));
    }
}

__global__ void scatter_kernel(const int* __restrict__ topi,
                               int* __restrict__ counts, int* __restrict__ tok_list)
{
    const int t = blockIdx.x * 256 + threadIdx.x;
    const int e = topi[t];
    const int pos = atomicAdd(&counts[e], 1);
    tok_list[e * TT + pos] = t;
}

// ---------------------------------------------------------------- grouped MoE GEMM 1
// gu[token, 0:2F] = (t[token]*gate[token]) @ gate_up_proj[e]
__global__ __launch_bounds__(256) void moe_gemm1_kernel(
    const float* __restrict__ tin, const float* __restrict__ gates,
    const float* __restrict__ gup, const int* __restrict__ tok_list,
    const int* __restrict__ counts, float* __restrict__ gu)
{
    const int e = blockIdx.z;
    const int cnt = counts[e];
    const int row0 = blockIdx.y * TILE;
    if (row0 >= cnt) return;
    const int col0 = blockIdx.x * TILE;
    const int NB = 2 * FF;
    const float* B = gup + (size_t)e * DD * NB;
    __shared__ alignas(16) float As[BKK][TILE];
    __shared__ alignas(16) float Bs[BKK][TILE];
    __shared__ int toks[TILE];
    __shared__ float scl[TILE];
    const int tid = threadIdx.x;
    if (tid < TILE) {
        const int r = row0 + tid;
        const int tk = (r < cnt) ? tok_list[e * TT + r] : -1;
        toks[tid] = tk;
        scl[tid] = (tk >= 0) ? gates[tk] : 0.0f;
    }
    __syncthreads();
    const int tx = tid & 15, ty = tid >> 4;
    const int am = tid >> 2, ak = (tid & 3) << 2;
    const int bk = tid >> 4, bn = (tid & 15) << 2;
    const int atok = toks[am];
    const float ascl = scl[am];
    const float* Aptr = tin + (size_t)(atok >= 0 ? atok : 0) * DD + ak;
    const float* Bptr = B + (size_t)bk * NB + col0 + bn;
    float acc[4][4] = {};
    for (int k0 = 0; k0 < DD; k0 += BKK) {
        float4 av = (atok >= 0) ? *(const float4*)(Aptr + k0) : make_float4(0, 0, 0, 0);
        float4 bv = *(const float4*)(Bptr + (size_t)k0 * NB);
        __syncthreads();
        As[ak + 0][am] = av.x * ascl;
        As[ak + 1][am] = av.y * ascl;
        As[ak + 2][am] = av.z * ascl;
        As[ak + 3][am] = av.w * ascl;
        *(float4*)&Bs[bk][bn] = bv;
        __syncthreads();
#pragma unroll
        for (int kk = 0; kk < BKK; ++kk) {
            const float4 a = *(const float4*)&As[kk][ty << 2];
            const float4 b = *(const float4*)&Bs[kk][tx << 2];
            const float ar[4] = {a.x, a.y, a.z, a.w};
            const float br[4] = {b.x, b.y, b.z, b.w};
#pragma unroll
            for (int i = 0; i < 4; ++i)
#pragma unroll
                for (int j = 0; j < 4; ++j)
                    acc[i][j] = fmaf(ar[i], br[j], acc[i][j]);
        }
    }
#pragma unroll
    for (int i = 0; i < 4; ++i) {
        const int tk = toks[(ty << 2) + i];
        if (tk < 0) continue;
        const size_t idx = (size_t)tk * NB + col0 + (tx << 2);
        *(float4*)&gu[idx] = make_float4(acc[i][0], acc[i][1], acc[i][2], acc[i][3]);
    }
}

// ---------------------------------------------------------------- grouped MoE GEMM 2
// out[token, :] += hmid[token] @ down_proj[e]
__global__ __launch_bounds__(256) void moe_gemm2_kernel(
    const float* __restrict__ hmid, const float* __restrict__ dproj,
    const int* __restrict__ tok_list, const int* __restrict__ counts,
    float* __restrict__ out)
{
    const int e = blockIdx.z;
    const int cnt = counts[e];
    const int row0 = blockIdx.y * TILE;
    if (row0 >= cnt) return;
    const int col0 = blockIdx.x * TILE;
    const float* B = dproj + (size_t)e * FF * DD;
    __shared__ alignas(16) float As[BKK][TILE];
    __shared__ alignas(16) float Bs[BKK][TILE];
    __shared__ int toks[TILE];
    const int tid = threadIdx.x;
    if (tid < TILE) {
        const int r = row0 + tid;
        toks[tid] = (r < cnt) ? tok_list[e * TT + r] : -1;
    }
    __syncthreads();
    const int tx = tid & 15, ty = tid >> 4;
    const int am = tid >> 2, ak = (tid & 3) << 2;
    const int bk = tid >> 4, bn = (tid & 15) << 2;
    const int atok = toks[am];
    const float* Aptr = hmid + (size_t)(atok >= 0 ? atok : 0) * FF + ak;
    const float* Bptr = B + (size_t)bk * DD + col0 + bn;
    float acc[4][4] = {};
    for (int k0 = 0; k0 < FF; k0 += BKK) {
        float4 av = (atok >= 0) ? *(const float4*)(Aptr + k0) : make_float4(0, 0, 0, 0);
        float4 bv = *(const float4*)(Bptr + (size_t)k0 * DD);
        __syncthreads();
        As[ak + 0][am] = av.x;
        As[ak + 1][am] = av.y;
        As[ak + 2][am] = av.z;
        As[ak + 3][am] = av.w;
        *(float4*)&Bs[bk][bn] = bv;
        __syncthreads();
#pragma unroll
        for (int kk = 0; kk < BKK; ++kk) {
            const float4 a = *(const float4*)&As[kk][ty << 2];
            const float4 b = *(const float4*)&Bs[kk][tx << 2];
            const float ar[4] = {a.x, a.y, a.z, a.w};
            const float br[4] = {b.x, b.y, b.z, b.w};
#pragma unroll
            for (int i = 0; i < 4; ++i)
#pragma unroll
                for (int j = 0; j < 4; ++j)
                    acc[i][j] = fmaf(ar[i], br[j], acc[i][j]);
        }
    }
#pragma unroll
    for (int i = 0; i < 4; ++i) {
        const int tk = toks[(ty << 2) + i];
        if (tk < 0) continue;
        const size_t idx = (size_t)tk * DD + col0 + (tx << 2);
        float4 o = *(const float4*)&out[idx];
        o.x += acc[i][0]; o.y += acc[i][1]; o.z += acc[i][2]; o.w += acc[i][3];
        *(float4*)&out[idx] = o;
    }
}

// ---------------------------------------------------------------- elementwise
__global__ void silu_mul_kernel(float* __restrict__ g, const float* __restrict__ u)
{
    const size_t i = (size_t)blockIdx.x * 256 + threadIdx.x;
    const float gv = g[i];
    g[i] = gv / (1.0f + __expf(-gv)) * u[i];
}

// h[t,f] = gu[t, F+f] * silu(gu[t, f])
__global__ void gu_act_kernel(const float* __restrict__ gu, float* __restrict__ h)
{
    const size_t i = (size_t)blockIdx.x * 256 + threadIdx.x;
    const size_t t = i >> 11;          // / FF
    const size_t f = i & (FF - 1);
    const float g = gu[t * (2 * FF) + f];
    const float u = gu[t * (2 * FF) + FF + f];
    h[i] = u * (g / (1.0f + __expf(-g)));
}

// ---------------------------------------------------------------- launch
extern "C" void kernel_launch(void* const* d_in, const int* in_sizes, int n_in,
                              void* d_out, int out_size, void* d_ws, size_t ws_size,
                              hipStream_t stream)
{
    const float* hidden = (const float*)d_in[0];
    const float* fcos   = (const float*)d_in[1];
    const float* fsin   = (const float*)d_in[2];
    const float* wq     = (const float*)d_in[5];
    const float* wk     = (const float*)d_in[6];
    const float* wv     = (const float*)d_in[7];
    const float* wo     = (const float*)d_in[8];
    const float* ln1    = (const float*)d_in[9];
    const float* ln2    = (const float*)d_in[10];
    const float* rw     = (const float*)d_in[11];
    const float* gup    = (const float*)d_in[12];
    const float* dproj  = (const float*)d_in[13];
    const float* sgw    = (const float*)d_in[14];
    const float* suw    = (const float*)d_in[15];
    const float* sdw    = (const float*)d_in[16];
    float* out = (float*)d_out;

    float* wsf = (float*)d_ws;
    const size_t M1 = 1024 * 1024;
    float* hsn = wsf;             // 4M floats: rms1 out -> t -> hmid
    float* qb  = wsf + 4 * M1;    // 4M: q -> shared gate (smid in place)
    float* kb  = wsf + 8 * M1;    // 1M
    float* vb  = wsf + 9 * M1;    // 1M
    float* ab  = wsf + 10 * M1;   // 4M: attn out -> shared up
    float* hs2 = wsf + 14 * M1;   // 4M: residual2
    float* gu  = wsf + 18 * M1;   // 8M: (T, 2F)
    int*   topi     = (int*)(wsf + 26 * M1);
    float* gate     = wsf + 26 * M1 + TT;
    int*   counts   = (int*)(wsf + 26 * M1 + 2 * TT);
    int*   tok_list = (int*)(wsf + 26 * M1 + 2 * TT + 64);

    hipMemsetAsync(counts, 0, NE * sizeof(int), stream);

    // attn block
    rmsnorm_kernel<<<TT, 256, 0, stream>>>(hidden, ln1, hsn);
    gemm_f32_kernel<<<dim3(2048 / TILE, TT / TILE), 256, 0, stream>>>(hsn, wq, qb, nullptr, TT, 2048, DD);
    gemm_f32_kernel<<<dim3(512 / TILE, TT / TILE), 256, 0, stream>>>(hsn, wk, kb, nullptr, TT, 512, DD);
    gemm_f32_kernel<<<dim3(512 / TILE, TT / TILE), 256, 0, stream>>>(hsn, wv, vb, nullptr, TT, 512, DD);
    rope_l2_kernel<<<TT * NHQ / 4, 256, 0, stream>>>(qb, NHQ, fcos, fsin);
    rope_l2_kernel<<<TT * KVH / 4, 256, 0, stream>>>(kb, KVH, fcos, fsin);
    attention_kernel<<<dim3(TT / 4, NHQ), 256, 0, stream>>>(qb, kb, vb, ab);
    gemm_f32_kernel<<<dim3(DD / TILE, TT / TILE), 256, 0, stream>>>(ab, wo, hs2, hidden, TT, DD, 2048);

    // moe block
    rmsnorm_kernel<<<TT, 256, 0, stream>>>(hs2, ln2, hsn);                      // t
    router_kernel<<<TT / 4, 256, 0, stream>>>(hsn, rw, topi, gate);
    scatter_kernel<<<TT / 256, 256, 0, stream>>>(topi, counts, tok_list);
    gemm_f32_kernel<<<dim3(FF / TILE, TT / TILE), 256, 0, stream>>>(hsn, sgw, qb, nullptr, TT, FF, DD);
    gemm_f32_kernel<<<dim3(FF / TILE, TT / TILE), 256, 0, stream>>>(hsn, suw, ab, nullptr, TT, FF, DD);
    moe_gemm1_kernel<<<dim3(2 * FF / TILE, TT / TILE, NE), 256, 0, stream>>>(hsn, gate, gup, tok_list, counts, gu);
    silu_mul_kernel<<<TT * FF / 256, 256, 0, stream>>>(qb, ab);                 // smid in qb
    gu_act_kernel<<<TT * FF / 256, 256, 0, stream>>>(gu, hsn);                  // hmid in hsn (t now dead)
    gemm_f32_kernel<<<dim3(DD / TILE, TT / TILE), 256, 0, stream>>>(qb, sdw, out, hs2, TT, DD, FF);  // out = hs2 + shared
    moe_gemm2_kernel<<<dim3(DD / TILE, TT / TILE, NE), 256, 0, stream>>>(hsn, dproj, tok_list, counts, out);  // out += routed
}

// Round 2
// 3112.354 us; speedup vs baseline: 1.8837x; 1.8837x over previous
//
#include <hip/hip_runtime.h>
#include <hip/hip_bf16.h>

// Problem constants (B=1)
#define TT 2048   // tokens = B*S
#define DD 2048   // hidden dim
#define NHQ 16    // query heads
#define KVH 4     // kv heads
#define HDIM 128  // head dim
#define NE 8      // experts
#define FF 2048   // ffn dim
#define SCALING 0.08838834764831845f  // 1/sqrt(128)
#define RMS_EPS 1e-5f
#define L2_EPS 1e-6f

#define TILE 64
#define BKK 16

// ---------------------------------------------------------------- rmsnorm
__global__ __launch_bounds__(256) void rmsnorm_kernel(
    const float* __restrict__ x, const float* __restrict__ w,
    float* __restrict__ y)
{
    const int tok = blockIdx.x;
    const float* xr = x + (size_t)tok * DD;
    float4 v[2];
    float ss = 0.0f;
#pragma unroll
    for (int i = 0; i < 2; ++i) {
        int d4 = threadIdx.x + i * 256;
        v[i] = *(const float4*)&xr[d4 * 4];
        ss += v[i].x * v[i].x + v[i].y * v[i].y + v[i].z * v[i].z + v[i].w * v[i].w;
    }
    for (int off = 32; off; off >>= 1) ss += __shfl_xor(ss, off);
    __shared__ float red[4];
    const int wid = threadIdx.x >> 6, lane = threadIdx.x & 63;
    if (lane == 0) red[wid] = ss;
    __syncthreads();
    const float tot = red[0] + red[1] + red[2] + red[3];
    const float rs = rsqrtf(tot * (1.0f / DD) + RMS_EPS);
    float* yr = y + (size_t)tok * DD;
#pragma unroll
    for (int i = 0; i < 2; ++i) {
        int d = (threadIdx.x + i * 256) * 4;
        float4 wv = *(const float4*)&w[d];
        float4 o;
        o.x = v[i].x * rs * wv.x;
        o.y = v[i].y * rs * wv.y;
        o.z = v[i].z * rs * wv.z;
        o.w = v[i].w * rs * wv.w;
        *(float4*)&yr[d] = o;
    }
}

// ---------------------------------------------------------------- fp32 tiled GEMM
// C[M,N] = A[M,K] @ B[K,N]  (+ addsrc) ; M,N multiples of 64, K multiple of 16
__global__ __launch_bounds__(256) void gemm_f32_kernel(
    const float* __restrict__ A, const float* __restrict__ B,
    float* __restrict__ C, const float* __restrict__ addsrc,
    int M, int N, int K)
{
    __shared__ alignas(16) float As[BKK][TILE];   // [k][m]
    __shared__ alignas(16) float Bs[BKK][TILE];   // [k][n]
    const int tid = threadIdx.x;
    const int tx = tid & 15, ty = tid >> 4;
    const int row0 = blockIdx.y * TILE, col0 = blockIdx.x * TILE;
    const int am = tid >> 2, ak = (tid & 3) << 2;
    const int bk = tid >> 4, bn = (tid & 15) << 2;
    const float* Aptr = A + (size_t)(row0 + am) * K + ak;
    const float* Bptr = B + (size_t)bk * N + col0 + bn;
    float acc[4][4] = {};
    for (int k0 = 0; k0 < K; k0 += BKK) {
        float4 av = *(const float4*)(Aptr + k0);
        float4 bv = *(const float4*)(Bptr + (size_t)k0 * N);
        __syncthreads();
        As[ak + 0][am] = av.x;
        As[ak + 1][am] = av.y;
        As[ak + 2][am] = av.z;
        As[ak + 3][am] = av.w;
        *(float4*)&Bs[bk][bn] = bv;
        __syncthreads();
#pragma unroll
        for (int kk = 0; kk < BKK; ++kk) {
            const float4 a = *(const float4*)&As[kk][ty << 2];
            const float4 b = *(const float4*)&Bs[kk][tx << 2];
            const float ar[4] = {a.x, a.y, a.z, a.w};
            const float br[4] = {b.x, b.y, b.z, b.w};
#pragma unroll
            for (int i = 0; i < 4; ++i)
#pragma unroll
                for (int j = 0; j < 4; ++j)
                    acc[i][j] = fmaf(ar[i], br[j], acc[i][j]);
        }
    }
#pragma unroll
    for (int i = 0; i < 4; ++i) {
        const size_t idx = (size_t)(row0 + (ty << 2) + i) * N + col0 + (tx << 2);
        float4 o = make_float4(acc[i][0], acc[i][1], acc[i][2], acc[i][3]);
        if (addsrc) {
            float4 r = *(const float4*)&addsrc[idx];
            o.x += r.x; o.y += r.y; o.z += r.z; o.w += r.w;
        }
        *(float4*)&C[idx] = o;
    }
}

// ---------------------------------------------------------------- RoPE + l2norm (in place)
__global__ __launch_bounds__(256) void rope_l2_kernel(
    float* __restrict__ x, int nh,
    const float* __restrict__ cosb, const float* __restrict__ sinb)
{
    const int wid = threadIdx.x >> 6, lane = threadIdx.x & 63;
    const int row = blockIdx.x * 4 + wid;
    const int tok = row / nh;
    float* xr = x + (size_t)row * HDIM;
    float2 ab = *(const float2*)&xr[lane * 2];
    const float c = cosb[tok * (HDIM / 2) + lane];
    const float s = sinb[tok * (HDIM / 2) + lane];
    const float o0 = ab.x * c - ab.y * s;
    const float o1 = ab.x * s + ab.y * c;
    float ss = o0 * o0 + o1 * o1;
    for (int off = 32; off; off >>= 1) ss += __shfl_xor(ss, off);
    const float r = rsqrtf(ss * (1.0f / HDIM) + L2_EPS);
    *(float2*)&xr[lane * 2] = make_float2(o0 * r, o1 * r);
}

// ---------------------------------------------------------------- flash attention (fp32 tiles)
// q: (TT,NHQ,HDIM), k/v: (TT,KVH,HDIM), o: (TT,NHQ,HDIM)
// One block per (64-row q-tile, head). K-tile=64. Scores/PV are 64x64
// register-blocked GEMMs (4x4 and 4x8 per thread). Online softmax in regs.
// LDS = 32K Qs + 32K K/V (reused) + 16K P = exactly 80 KB -> 2 blocks/CU.
__global__ __launch_bounds__(256) void attn_flash_kernel(
    const float* __restrict__ q, const float* __restrict__ k,
    const float* __restrict__ v, float* __restrict__ o)
{
    __shared__ alignas(16) float Qs[128 * 64];  // [d][r]
    __shared__ alignas(16) float KA[128 * 64];  // K as [d][c]; later V as [c][d]
    __shared__ alignas(16) float PB[64 * 64];   // [r][c]

    // anti-paired swizzle: block b and b+256 get complementary causal work
    const int b = blockIdx.x;
    int qt, h;
    if (b < 256) { qt = b >> 4; h = b & 15; }
    else { const int c = b - 256; qt = 31 - (c >> 4); h = c & 15; }
    const int q0 = qt * 64;
    const int kvh = h >> 2;

    const int tid = threadIdx.x;
    const int tx = tid & 15, ty = tid >> 4;
    const int lr = tid & 63, dg = tid >> 6;

    // stage Q transposed: Qs[d][r]
#pragma unroll
    for (int t = 0; t < 8; ++t) {
        const int d = dg * 32 + t * 4;
        const float4 qv = *(const float4*)&q[(((size_t)(q0 + lr)) * NHQ + h) * HDIM + d];
        Qs[(d + 0) * 64 + lr] = qv.x;
        Qs[(d + 1) * 64 + lr] = qv.y;
        Qs[(d + 2) * 64 + lr] = qv.z;
        Qs[(d + 3) * 64 + lr] = qv.w;
    }

    float O[4][8] = {};
    float m_i[4], l_i[4] = {};
#pragma unroll
    for (int i = 0; i < 4; ++i) m_i[i] = -1e30f;

    for (int t0 = 0; t0 <= qt; ++t0) {
        const int j0 = t0 * 64;
        __syncthreads();  // prev PV done reading KA (and Q stage done on iter 0)
        // stage K transposed: KA[d][c]
#pragma unroll
        for (int t = 0; t < 8; ++t) {
            const int d = dg * 32 + t * 4;
            const float4 kv4 = *(const float4*)&k[(((size_t)(j0 + lr)) * KVH + kvh) * HDIM + d];
            KA[(d + 0) * 64 + lr] = kv4.x;
            KA[(d + 1) * 64 + lr] = kv4.y;
            KA[(d + 2) * 64 + lr] = kv4.z;
            KA[(d + 3) * 64 + lr] = kv4.w;
        }
        __syncthreads();
        // scores: S = Q @ K^T   (4x4 per thread; row=ty*4+i, col=tx*4+j)
        float s[4][4] = {};
#pragma unroll 4
        for (int kk = 0; kk < 128; ++kk) {
            const float4 a = *(const float4*)&Qs[kk * 64 + (ty << 2)];
            const float4 bb = *(const float4*)&KA[kk * 64 + (tx << 2)];
            const float ar[4] = {a.x, a.y, a.z, a.w};
            const float br[4] = {bb.x, bb.y, bb.z, bb.w};
#pragma unroll
            for (int i = 0; i < 4; ++i)
#pragma unroll
                for (int j = 0; j < 4; ++j)
                    s[i][j] = fmaf(ar[i], br[j], s[i][j]);
        }
#pragma unroll
        for (int i = 0; i < 4; ++i)
#pragma unroll
            for (int j = 0; j < 4; ++j)
                s[i][j] *= SCALING;
        if (t0 == qt) {  // diagonal tile: mask c > r
#pragma unroll
            for (int i = 0; i < 4; ++i)
#pragma unroll
                for (int j = 0; j < 4; ++j)
                    if ((tx << 2) + j > (ty << 2) + i) s[i][j] = -1e30f;
        }
        // online softmax: row stats live replicated across the 16 tx lanes
        float alpha[4], rowsum[4];
#pragma unroll
        for (int i = 0; i < 4; ++i) {
            float mt = fmaxf(fmaxf(s[i][0], s[i][1]), fmaxf(s[i][2], s[i][3]));
#pragma unroll
            for (int off = 1; off < 16; off <<= 1) mt = fmaxf(mt, __shfl_xor(mt, off));
            const float mn = fmaxf(m_i[i], mt);
            alpha[i] = __expf(m_i[i] - mn);
            m_i[i] = mn;
            float rsum = 0.0f;
#pragma unroll
            for (int j = 0; j < 4; ++j) {
                const float p = __expf(s[i][j] - mn);  // masked -> exp(-huge) = 0
                s[i][j] = p;
                rsum += p;
            }
#pragma unroll
            for (int off = 1; off < 16; off <<= 1) rsum += __shfl_xor(rsum, off);
            rowsum[i] = rsum;
        }
#pragma unroll
        for (int i = 0; i < 4; ++i) {
            l_i[i] = l_i[i] * alpha[i] + rowsum[i];
#pragma unroll
            for (int j = 0; j < 8; ++j) O[i][j] *= alpha[i];
        }
        __syncthreads();  // all threads done reading KA(K) before V overwrites it
        // write P; stage V into KA as [c][d]
#pragma unroll
        for (int i = 0; i < 4; ++i)
            *(float4*)&PB[((ty << 2) + i) * 64 + (tx << 2)] =
                make_float4(s[i][0], s[i][1], s[i][2], s[i][3]);
#pragma unroll
        for (int t = 0; t < 8; ++t) {
            const int idx = tid + t * 256;
            const int row = idx >> 5, c4 = (idx & 31) * 4;
            *(float4*)&KA[row * 128 + c4] =
                *(const float4*)&v[(((size_t)(j0 + row)) * KVH + kvh) * HDIM + c4];
        }
        __syncthreads();
        // O += P @ V   (rows ty*4+i, cols tx*8..tx*8+7)
#pragma unroll 2
        for (int c = 0; c < 64; ++c) {
            const float4 v0 = *(const float4*)&KA[c * 128 + (tx << 3)];
            const float4 v1 = *(const float4*)&KA[c * 128 + (tx << 3) + 4];
#pragma unroll
            for (int i = 0; i < 4; ++i) {
                const float p = PB[((ty << 2) + i) * 64 + c];
                O[i][0] = fmaf(p, v0.x, O[i][0]);
                O[i][1] = fmaf(p, v0.y, O[i][1]);
                O[i][2] = fmaf(p, v0.z, O[i][2]);
                O[i][3] = fmaf(p, v0.w, O[i][3]);
                O[i][4] = fmaf(p, v1.x, O[i][4]);
                O[i][5] = fmaf(p, v1.y, O[i][5]);
                O[i][6] = fmaf(p, v1.z, O[i][6]);
                O[i][7] = fmaf(p, v1.w, O[i][7]);
            }
        }
    }
    // epilogue
#pragma unroll
    for (int i = 0; i < 4; ++i) {
        const float inv = 1.0f / l_i[i];
        float* orow = (float*)&o[(((size_t)(q0 + (ty << 2) + i)) * NHQ + h) * HDIM + (tx << 3)];
        *(float4*)orow = make_float4(O[i][0] * inv, O[i][1] * inv, O[i][2] * inv, O[i][3] * inv);
        *(float4*)(orow + 4) = make_float4(O[i][4] * inv, O[i][5] * inv, O[i][6] * inv, O[i][7] * inv);
    }
}

// ---------------------------------------------------------------- router (top-1 + sigmoid gate)
__global__ __launch_bounds__(256) void router_kernel(
    const float* __restrict__ t, const float* __restrict__ rw,
    int* __restrict__ topi, float* __restrict__ gate)
{
    const int wid = threadIdx.x >> 6, lane = threadIdx.x & 63;
    const int tok = blockIdx.x * 4 + wid;
    const float* x = t + (size_t)tok * DD;
    float acc[NE] = {};
    for (int d = lane; d < DD; d += 64) {
        const float xv = x[d];
        const float4 r0 = *(const float4*)&rw[d * NE];
        const float4 r1 = *(const float4*)&rw[d * NE + 4];
        acc[0] = fmaf(xv, r0.x, acc[0]); acc[1] = fmaf(xv, r0.y, acc[1]);
        acc[2] = fmaf(xv, r0.z, acc[2]); acc[3] = fmaf(xv, r0.w, acc[3]);
        acc[4] = fmaf(xv, r1.x, acc[4]); acc[5] = fmaf(xv, r1.y, acc[5]);
        acc[6] = fmaf(xv, r1.z, acc[6]); acc[7] = fmaf(xv, r1.w, acc[7]);
    }
#pragma unroll
    for (int e = 0; e < NE; ++e)
        for (int off = 32; off; off >>= 1) acc[e] += __shfl_xor(acc[e], off);
    if (lane == 0) {
        int best = 0;
        float bv = acc[0];
#pragma unroll
        for (int e = 1; e < NE; ++e)
            if (acc[e] > bv) { bv = acc[e]; best = e; }
        topi[tok] = best;
        gate[tok] = 1.0f / (1.0f + __expf(-bv));
    }
}

__global__ void scatter_kernel(const int* __restrict__ topi,
                               int* __restrict__ counts, int* __restrict__ tok_list)
{
    const int t = blockIdx.x * 256 + threadIdx.x;
    const int e = topi[t];
    const int pos = atomicAdd(&counts[e], 1);
    tok_list[e * TT + pos] = t;
}

// ---------------------------------------------------------------- grouped MoE GEMM 1
__global__ __launch_bounds__(256) void moe_gemm1_kernel(
    const float* __restrict__ tin, const float* __restrict__ gates,
    const float* __restrict__ gup, const int* __restrict__ tok_list,
    const int* __restrict__ counts, float* __restrict__ gu)
{
    const int e = blockIdx.z;
    const int cnt = counts[e];
    const int row0 = blockIdx.y * TILE;
    if (row0 >= cnt) return;
    const int col0 = blockIdx.x * TILE;
    const int NB = 2 * FF;
    const float* B = gup + (size_t)e * DD * NB;
    __shared__ alignas(16) float As[BKK][TILE];
    __shared__ alignas(16) float Bs[BKK][TILE];
    __shared__ int toks[TILE];
    __shared__ float scl[TILE];
    const int tid = threadIdx.x;
    if (tid < TILE) {
        const int r = row0 + tid;
        const int tk = (r < cnt) ? tok_list[e * TT + r] : -1;
        toks[tid] = tk;
        scl[tid] = (tk >= 0) ? gates[tk] : 0.0f;
    }
    __syncthreads();
    const int tx = tid & 15, ty = tid >> 4;
    const int am = tid >> 2, ak = (tid & 3) << 2;
    const int bk = tid >> 4, bn = (tid & 15) << 2;
    const int atok = toks[am];
    const float ascl = scl[am];
    const float* Aptr = tin + (size_t)(atok >= 0 ? atok : 0) * DD + ak;
    const float* Bptr = B + (size_t)bk * NB + col0 + bn;
    float acc[4][4] = {};
    for (int k0 = 0; k0 < DD; k0 += BKK) {
        float4 av = (atok >= 0) ? *(const float4*)(Aptr + k0) : make_float4(0, 0, 0, 0);
        float4 bv = *(const float4*)(Bptr + (size_t)k0 * NB);
        __syncthreads();
        As[ak + 0][am] = av.x * ascl;
        As[ak + 1][am] = av.y * ascl;
        As[ak + 2][am] = av.z * ascl;
        As[ak + 3][am] = av.w * ascl;
        *(float4*)&Bs[bk][bn] = bv;
        __syncthreads();
#pragma unroll
        for (int kk = 0; kk < BKK; ++kk) {
            const float4 a = *(const float4*)&As[kk][ty << 2];
            const float4 b = *(const float4*)&Bs[kk][tx << 2];
            const float ar[4] = {a.x, a.y, a.z, a.w};
            const float br[4] = {b.x, b.y, b.z, b.w};
#pragma unroll
            for (int i = 0; i < 4; ++i)
#pragma unroll
                for (int j = 0; j < 4; ++j)
                    acc[i][j] = fmaf(ar[i], br[j], acc[i][j]);
        }
    }
#pragma unroll
    for (int i = 0; i < 4; ++i) {
        const int tk = toks[(ty << 2) + i];
        if (tk < 0) continue;
        const size_t idx = (size_t)tk * NB + col0 + (tx << 2);
        *(float4*)&gu[idx] = make_float4(acc[i][0], acc[i][1], acc[i][2], acc[i][3]);
    }
}

// ---------------------------------------------------------------- grouped MoE GEMM 2
__global__ __launch_bounds__(256) void moe_gemm2_kernel(
    const float* __restrict__ hmid, const float* __restrict__ dproj,
    const int* __restrict__ tok_list, const int* __restrict__ counts,
    float* __restrict__ out)
{
    const int e = blockIdx.z;
    const int cnt = counts[e];
    const int row0 = blockIdx.y * TILE;
    if (row0 >= cnt) return;
    const int col0 = blockIdx.x * TILE;
    const float* B = dproj + (size_t)e * FF * DD;
    __shared__ alignas(16) float As[BKK][TILE];
    __shared__ alignas(16) float Bs[BKK][TILE];
    __shared__ int toks[TILE];
    const int tid = threadIdx.x;
    if (tid < TILE) {
        const int r = row0 + tid;
        toks[tid] = (r < cnt) ? tok_list[e * TT + r] : -1;
    }
    __syncthreads();
    const int tx = tid & 15, ty = tid >> 4;
    const int am = tid >> 2, ak = (tid & 3) << 2;
    const int bk = tid >> 4, bn = (tid & 15) << 2;
    const int atok = toks[am];
    const float* Aptr = hmid + (size_t)(atok >= 0 ? atok : 0) * FF + ak;
    const float* Bptr = B + (size_t)bk * DD + col0 + bn;
    float acc[4][4] = {};
    for (int k0 = 0; k0 < FF; k0 += BKK) {
        float4 av = (atok >= 0) ? *(const float4*)(Aptr + k0) : make_float4(0, 0, 0, 0);
        float4 bv = *(const float4*)(Bptr + (size_t)k0 * DD);
        __syncthreads();
        As[ak + 0][am] = av.x;
        As[ak + 1][am] = av.y;
        As[ak + 2][am] = av.z;
        As[ak + 3][am] = av.w;
        *(float4*)&Bs[bk][bn] = bv;
        __syncthreads();
#pragma unroll
        for (int kk = 0; kk < BKK; ++kk) {
            const float4 a = *(const float4*)&As[kk][ty << 2];
            const float4 b = *(const float4*)&Bs[kk][tx << 2];
            const float ar[4] = {a.x, a.y, a.z, a.w};
            const float br[4] = {b.x, b.y, b.z, b.w};
#pragma unroll
            for (int i = 0; i < 4; ++i)
#pragma unroll
                for (int j = 0; j < 4; ++j)
                    acc[i][j] = fmaf(ar[i], br[j], acc[i][j]);
        }
    }
#pragma unroll
    for (int i = 0; i < 4; ++i) {
        const int tk = toks[(ty << 2) + i];
        if (tk < 0) continue;
        const size_t idx = (size_t)tk * DD + col0 + (tx << 2);
        float4 o = *(const float4*)&out[idx];
        o.x += acc[i][0]; o.y += acc[i][1]; o.z += acc[i][2]; o.w += acc[i][3];
        *(float4*)&out[idx] = o;
    }
}

// ---------------------------------------------------------------- elementwise
__global__ void silu_mul_kernel(float* __restrict__ g, const float* __restrict__ u)
{
    const size_t i = (size_t)blockIdx.x * 256 + threadIdx.x;
    const float gv = g[i];
    g[i] = gv / (1.0f + __expf(-gv)) * u[i];
}

__global__ void gu_act_kernel(const float* __restrict__ gu, float* __restrict__ h)
{
    const size_t i = (size_t)blockIdx.x * 256 + threadIdx.x;
    const size_t t = i >> 11;          // / FF
    const size_t f = i & (FF - 1);
    const float g = gu[t * (2 * FF) + f];
    const float u = gu[t * (2 * FF) + FF + f];
    h[i] = u * (g / (1.0f + __expf(-g)));
}

// ---------------------------------------------------------------- launch
extern "C" void kernel_launch(void* const* d_in, const int* in_sizes, int n_in,
                              void* d_out, int out_size, void* d_ws, size_t ws_size,
                              hipStream_t stream)
{
    const float* hidden = (const float*)d_in[0];
    const float* fcos   = (const float*)d_in[1];
    const float* fsin   = (const float*)d_in[2];
    const float* wq     = (const float*)d_in[5];
    const float* wk     = (const float*)d_in[6];
    const float* wv     = (const float*)d_in[7];
    const float* wo     = (const float*)d_in[8];
    const float* ln1    = (const float*)d_in[9];
    const float* ln2    = (const float*)d_in[10];
    const float* rw     = (const float*)d_in[11];
    const float* gup    = (const float*)d_in[12];
    const float* dproj  = (const float*)d_in[13];
    const float* sgw    = (const float*)d_in[14];
    const float* suw    = (const float*)d_in[15];
    const float* sdw    = (const float*)d_in[16];
    float* out = (float*)d_out;

    float* wsf = (float*)d_ws;
    const size_t M1 = 1024 * 1024;
    float* hsn = wsf;             // 4M floats: rms1 out -> t -> hmid
    float* qb  = wsf + 4 * M1;    // 4M: q -> shared gate (smid in place)
    float* kb  = wsf + 8 * M1;    // 1M
    float* vb  = wsf + 9 * M1;    // 1M
    float* ab  = wsf + 10 * M1;   // 4M: attn out -> shared up
    float* hs2 = wsf + 14 * M1;   // 4M: residual2
    float* gu  = wsf + 18 * M1;   // 8M: (T, 2F)
    int*   topi     = (int*)(wsf + 26 * M1);
    float* gate     = wsf + 26 * M1 + TT;
    int*   counts   = (int*)(wsf + 26 * M1 + 2 * TT);
    int*   tok_list = (int*)(wsf + 26 * M1 + 2 * TT + 64);

    hipMemsetAsync(counts, 0, NE * sizeof(int), stream);

    // attn block
    rmsnorm_kernel<<<TT, 256, 0, stream>>>(hidden, ln1, hsn);
    gemm_f32_kernel<<<dim3(2048 / TILE, TT / TILE), 256, 0, stream>>>(hsn, wq, qb, nullptr, TT, 2048, DD);
    gemm_f32_kernel<<<dim3(512 / TILE, TT / TILE), 256, 0, stream>>>(hsn, wk, kb, nullptr, TT, 512, DD);
    gemm_f32_kernel<<<dim3(512 / TILE, TT / TILE), 256, 0, stream>>>(hsn, wv, vb, nullptr, TT, 512, DD);
    rope_l2_kernel<<<TT * NHQ / 4, 256, 0, stream>>>(qb, NHQ, fcos, fsin);
    rope_l2_kernel<<<TT * KVH / 4, 256, 0, stream>>>(kb, KVH, fcos, fsin);
    attn_flash_kernel<<<512, 256, 0, stream>>>(qb, kb, vb, ab);
    gemm_f32_kernel<<<dim3(DD / TILE, TT / TILE), 256, 0, stream>>>(ab, wo, hs2, hidden, TT, DD, 2048);

    // moe block
    rmsnorm_kernel<<<TT, 256, 0, stream>>>(hs2, ln2, hsn);                      // t
    router_kernel<<<TT / 4, 256, 0, stream>>>(hsn, rw, topi, gate);
    scatter_kernel<<<TT / 256, 256, 0, stream>>>(topi, counts, tok_list);
    gemm_f32_kernel<<<dim3(FF / TILE, TT / TILE), 256, 0, stream>>>(hsn, sgw, qb, nullptr, TT, FF, DD);
    gemm_f32_kernel<<<dim3(FF / TILE, TT / TILE), 256, 0, stream>>>(hsn, suw, ab, nullptr, TT, FF, DD);
    moe_gemm1_kernel<<<dim3(2 * FF / TILE, TT / TILE, NE), 256, 0, stream>>>(hsn, gate, gup, tok_list, counts, gu);
    silu_mul_kernel<<<TT * FF / 256, 256, 0, stream>>>(qb, ab);                 // smid in qb
    gu_act_kernel<<<TT * FF / 256, 256, 0, stream>>>(gu, hsn);                  // hmid in hsn (t now dead)
    gemm_f32_kernel<<<dim3(DD / TILE, TT / TILE), 256, 0, stream>>>(qb, sdw, out, hs2, TT, DD, FF);  // out = hs2 + shared
    moe_gemm2_kernel<<<dim3(DD / TILE, TT / TILE, NE), 256, 0, stream>>>(hsn, dproj, tok_list, counts, out);  // out += routed
}

// Round 3
// 2106.436 us; speedup vs baseline: 2.7833x; 1.4775x over previous
//
#include <hip/hip_runtime.h>
#include <hip/hip_bf16.h>

// Problem constants (B=1)
#define TT 2048   // tokens = B*S
#define DD 2048   // hidden dim
#define NHQ 16    // query heads
#define KVH 4     // kv heads
#define HDIM 128  // head dim
#define NE 8      // experts
#define FF 2048   // ffn dim
#define SCALING 0.08838834764831845f  // 1/sqrt(128)
#define RMS_EPS 1e-5f
#define L2_EPS 1e-6f

#define TILE 64
#define BKK 16

typedef __attribute__((ext_vector_type(8))) short short8;
typedef __attribute__((ext_vector_type(4))) float f32x4;

__device__ __forceinline__ float bf2f(ushort u) {
    union { unsigned int i; float f; } c; c.i = ((unsigned int)u) << 16; return c.f;
}
__device__ __forceinline__ ushort f2bf(float f) {
    union { unsigned int i; float f; } c; c.f = f;
    unsigned int r = c.i + 0x7fffu + ((c.i >> 16) & 1u);   // RNE
    return (ushort)(r >> 16);
}
__device__ __forceinline__ void gload_lds16(const void* g, void* l) {
    __builtin_amdgcn_global_load_lds((const __attribute__((address_space(1))) void*)g,
                                     (__attribute__((address_space(3))) void*)l, 16, 0, 0);
}

// ---------------------------------------------------------------- rmsnorm (fp32 out)
__global__ __launch_bounds__(256) void rmsnorm_kernel(
    const float* __restrict__ x, const float* __restrict__ w,
    float* __restrict__ y)
{
    const int tok = blockIdx.x;
    const float* xr = x + (size_t)tok * DD;
    float4 v[2];
    float ss = 0.0f;
#pragma unroll
    for (int i = 0; i < 2; ++i) {
        int d4 = threadIdx.x + i * 256;
        v[i] = *(const float4*)&xr[d4 * 4];
        ss += v[i].x * v[i].x + v[i].y * v[i].y + v[i].z * v[i].z + v[i].w * v[i].w;
    }
    for (int off = 32; off; off >>= 1) ss += __shfl_xor(ss, off);
    __shared__ float red[4];
    const int wid = threadIdx.x >> 6, lane = threadIdx.x & 63;
    if (lane == 0) red[wid] = ss;
    __syncthreads();
    const float tot = red[0] + red[1] + red[2] + red[3];
    const float rs = rsqrtf(tot * (1.0f / DD) + RMS_EPS);
    float* yr = y + (size_t)tok * DD;
#pragma unroll
    for (int i = 0; i < 2; ++i) {
        int d = (threadIdx.x + i * 256) * 4;
        float4 wv = *(const float4*)&w[d];
        float4 o;
        o.x = v[i].x * rs * wv.x;
        o.y = v[i].y * rs * wv.y;
        o.z = v[i].z * rs * wv.z;
        o.w = v[i].w * rs * wv.w;
        *(float4*)&yr[d] = o;
    }
}

// rmsnorm writing BOTH fp32 (router needs full precision) and bf16 (GEMM A-side)
__global__ __launch_bounds__(256) void rmsnorm_dual_kernel(
    const float* __restrict__ x, const float* __restrict__ w,
    float* __restrict__ y, ushort* __restrict__ yb)
{
    const int tok = blockIdx.x;
    const float* xr = x + (size_t)tok * DD;
    float4 v[2];
    float ss = 0.0f;
#pragma unroll
    for (int i = 0; i < 2; ++i) {
        int d4 = threadIdx.x + i * 256;
        v[i] = *(const float4*)&xr[d4 * 4];
        ss += v[i].x * v[i].x + v[i].y * v[i].y + v[i].z * v[i].z + v[i].w * v[i].w;
    }
    for (int off = 32; off; off >>= 1) ss += __shfl_xor(ss, off);
    __shared__ float red[4];
    const int wid = threadIdx.x >> 6, lane = threadIdx.x & 63;
    if (lane == 0) red[wid] = ss;
    __syncthreads();
    const float tot = red[0] + red[1] + red[2] + red[3];
    const float rs = rsqrtf(tot * (1.0f / DD) + RMS_EPS);
    float* yr = y + (size_t)tok * DD;
    ushort* ybr = yb + (size_t)tok * DD;
#pragma unroll
    for (int i = 0; i < 2; ++i) {
        int d = (threadIdx.x + i * 256) * 4;
        float4 wv = *(const float4*)&w[d];
        float4 o;
        o.x = v[i].x * rs * wv.x;
        o.y = v[i].y * rs * wv.y;
        o.z = v[i].z * rs * wv.z;
        o.w = v[i].w * rs * wv.w;
        *(float4*)&yr[d] = o;
        ushort4 ob;
        ob.x = f2bf(o.x); ob.y = f2bf(o.y); ob.z = f2bf(o.z); ob.w = f2bf(o.w);
        *(ushort4*)&ybr[d] = ob;
    }
}

// ---------------------------------------------------------------- fp32 tiled GEMM (pre-router path)
__global__ __launch_bounds__(256) void gemm_f32_kernel(
    const float* __restrict__ A, const float* __restrict__ B,
    float* __restrict__ C, const float* __restrict__ addsrc,
    int M, int N, int K)
{
    __shared__ alignas(16) float As[BKK][TILE];
    __shared__ alignas(16) float Bs[BKK][TILE];
    const int tid = threadIdx.x;
    const int tx = tid & 15, ty = tid >> 4;
    const int row0 = blockIdx.y * TILE, col0 = blockIdx.x * TILE;
    const int am = tid >> 2, ak = (tid & 3) << 2;
    const int bk = tid >> 4, bn = (tid & 15) << 2;
    const float* Aptr = A + (size_t)(row0 + am) * K + ak;
    const float* Bptr = B + (size_t)bk * N + col0 + bn;
    float acc[4][4] = {};
    for (int k0 = 0; k0 < K; k0 += BKK) {
        float4 av = *(const float4*)(Aptr + k0);
        float4 bv = *(const float4*)(Bptr + (size_t)k0 * N);
        __syncthreads();
        As[ak + 0][am] = av.x;
        As[ak + 1][am] = av.y;
        As[ak + 2][am] = av.z;
        As[ak + 3][am] = av.w;
        *(float4*)&Bs[bk][bn] = bv;
        __syncthreads();
#pragma unroll
        for (int kk = 0; kk < BKK; ++kk) {
            const float4 a = *(const float4*)&As[kk][ty << 2];
            const float4 b = *(const float4*)&Bs[kk][tx << 2];
            const float ar[4] = {a.x, a.y, a.z, a.w};
            const float br[4] = {b.x, b.y, b.z, b.w};
#pragma unroll
            for (int i = 0; i < 4; ++i)
#pragma unroll
                for (int j = 0; j < 4; ++j)
                    acc[i][j] = fmaf(ar[i], br[j], acc[i][j]);
        }
    }
#pragma unroll
    for (int i = 0; i < 4; ++i) {
        const size_t idx = (size_t)(row0 + (ty << 2) + i) * N + col0 + (tx << 2);
        float4 o = make_float4(acc[i][0], acc[i][1], acc[i][2], acc[i][3]);
        if (addsrc) {
            float4 r = *(const float4*)&addsrc[idx];
            o.x += r.x; o.y += r.y; o.z += r.z; o.w += r.w;
        }
        *(float4*)&C[idx] = o;
    }
}

// ---------------------------------------------------------------- RoPE + l2norm (in place)
__global__ __launch_bounds__(256) void rope_l2_kernel(
    float* __restrict__ x, int nh,
    const float* __restrict__ cosb, const float* __restrict__ sinb)
{
    const int wid = threadIdx.x >> 6, lane = threadIdx.x & 63;
    const int row = blockIdx.x * 4 + wid;
    const int tok = row / nh;
    float* xr = x + (size_t)row * HDIM;
    float2 ab = *(const float2*)&xr[lane * 2];
    const float c = cosb[tok * (HDIM / 2) + lane];
    const float s = sinb[tok * (HDIM / 2) + lane];
    const float o0 = ab.x * c - ab.y * s;
    const float o1 = ab.x * s + ab.y * c;
    float ss = o0 * o0 + o1 * o1;
    for (int off = 32; off; off >>= 1) ss += __shfl_xor(ss, off);
    const float r = rsqrtf(ss * (1.0f / HDIM) + L2_EPS);
    *(float2*)&xr[lane * 2] = make_float2(o0 * r, o1 * r);
}

// ---------------------------------------------------------------- flash attention (fp32)
__global__ __launch_bounds__(256) void attn_flash_kernel(
    const float* __restrict__ q, const float* __restrict__ k,
    const float* __restrict__ v, float* __restrict__ o)
{
    __shared__ alignas(16) float Qs[128 * 64];
    __shared__ alignas(16) float KA[128 * 64];
    __shared__ alignas(16) float PB[64 * 64];

    const int b = blockIdx.x;
    int qt, h;
    if (b < 256) { qt = b >> 4; h = b & 15; }
    else { const int c = b - 256; qt = 31 - (c >> 4); h = c & 15; }
    const int q0 = qt * 64;
    const int kvh = h >> 2;

    const int tid = threadIdx.x;
    const int tx = tid & 15, ty = tid >> 4;
    const int lr = tid & 63, dg = tid >> 6;

#pragma unroll
    for (int t = 0; t < 8; ++t) {
        const int d = dg * 32 + t * 4;
        const float4 qv = *(const float4*)&q[(((size_t)(q0 + lr)) * NHQ + h) * HDIM + d];
        Qs[(d + 0) * 64 + lr] = qv.x;
        Qs[(d + 1) * 64 + lr] = qv.y;
        Qs[(d + 2) * 64 + lr] = qv.z;
        Qs[(d + 3) * 64 + lr] = qv.w;
    }

    float O[4][8] = {};
    float m_i[4], l_i[4] = {};
#pragma unroll
    for (int i = 0; i < 4; ++i) m_i[i] = -1e30f;

    for (int t0 = 0; t0 <= qt; ++t0) {
        const int j0 = t0 * 64;
        __syncthreads();
#pragma unroll
        for (int t = 0; t < 8; ++t) {
            const int d = dg * 32 + t * 4;
            const float4 kv4 = *(const float4*)&k[(((size_t)(j0 + lr)) * KVH + kvh) * HDIM + d];
            KA[(d + 0) * 64 + lr] = kv4.x;
            KA[(d + 1) * 64 + lr] = kv4.y;
            KA[(d + 2) * 64 + lr] = kv4.z;
            KA[(d + 3) * 64 + lr] = kv4.w;
        }
        __syncthreads();
        float s[4][4] = {};
#pragma unroll 4
        for (int kk = 0; kk < 128; ++kk) {
            const float4 a = *(const float4*)&Qs[kk * 64 + (ty << 2)];
            const float4 bb = *(const float4*)&KA[kk * 64 + (tx << 2)];
            const float ar[4] = {a.x, a.y, a.z, a.w};
            const float br[4] = {bb.x, bb.y, bb.z, bb.w};
#pragma unroll
            for (int i = 0; i < 4; ++i)
#pragma unroll
                for (int j = 0; j < 4; ++j)
                    s[i][j] = fmaf(ar[i], br[j], s[i][j]);
        }
#pragma unroll
        for (int i = 0; i < 4; ++i)
#pragma unroll
            for (int j = 0; j < 4; ++j)
                s[i][j] *= SCALING;
        if (t0 == qt) {
#pragma unroll
            for (int i = 0; i < 4; ++i)
#pragma unroll
                for (int j = 0; j < 4; ++j)
                    if ((tx << 2) + j > (ty << 2) + i) s[i][j] = -1e30f;
        }
        float alpha[4], rowsum[4];
#pragma unroll
        for (int i = 0; i < 4; ++i) {
            float mt = fmaxf(fmaxf(s[i][0], s[i][1]), fmaxf(s[i][2], s[i][3]));
#pragma unroll
            for (int off = 1; off < 16; off <<= 1) mt = fmaxf(mt, __shfl_xor(mt, off));
            const float mn = fmaxf(m_i[i], mt);
            alpha[i] = __expf(m_i[i] - mn);
            m_i[i] = mn;
            float rsum = 0.0f;
#pragma unroll
            for (int j = 0; j < 4; ++j) {
                const float p = __expf(s[i][j] - mn);
                s[i][j] = p;
                rsum += p;
            }
#pragma unroll
            for (int off = 1; off < 16; off <<= 1) rsum += __shfl_xor(rsum, off);
            rowsum[i] = rsum;
        }
#pragma unroll
        for (int i = 0; i < 4; ++i) {
            l_i[i] = l_i[i] * alpha[i] + rowsum[i];
#pragma unroll
            for (int j = 0; j < 8; ++j) O[i][j] *= alpha[i];
        }
        __syncthreads();
#pragma unroll
        for (int i = 0; i < 4; ++i)
            *(float4*)&PB[((ty << 2) + i) * 64 + (tx << 2)] =
                make_float4(s[i][0], s[i][1], s[i][2], s[i][3]);
#pragma unroll
        for (int t = 0; t < 8; ++t) {
            const int idx = tid + t * 256;
            const int row = idx >> 5, c4 = (idx & 31) * 4;
            *(float4*)&KA[row * 128 + c4] =
                *(const float4*)&v[(((size_t)(j0 + row)) * KVH + kvh) * HDIM + c4];
        }
        __syncthreads();
#pragma unroll 2
        for (int c = 0; c < 64; ++c) {
            const float4 v0 = *(const float4*)&KA[c * 128 + (tx << 3)];
            const float4 v1 = *(const float4*)&KA[c * 128 + (tx << 3) + 4];
#pragma unroll
            for (int i = 0; i < 4; ++i) {
                const float p = PB[((ty << 2) + i) * 64 + c];
                O[i][0] = fmaf(p, v0.x, O[i][0]);
                O[i][1] = fmaf(p, v0.y, O[i][1]);
                O[i][2] = fmaf(p, v0.z, O[i][2]);
                O[i][3] = fmaf(p, v0.w, O[i][3]);
                O[i][4] = fmaf(p, v1.x, O[i][4]);
                O[i][5] = fmaf(p, v1.y, O[i][5]);
                O[i][6] = fmaf(p, v1.z, O[i][6]);
                O[i][7] = fmaf(p, v1.w, O[i][7]);
            }
        }
    }
#pragma unroll
    for (int i = 0; i < 4; ++i) {
        const float inv = 1.0f / l_i[i];
        float* orow = (float*)&o[(((size_t)(q0 + (ty << 2) + i)) * NHQ + h) * HDIM + (tx << 3)];
        *(float4*)orow = make_float4(O[i][0] * inv, O[i][1] * inv, O[i][2] * inv, O[i][3] * inv);
        *(float4*)(orow + 4) = make_float4(O[i][4] * inv, O[i][5] * inv, O[i][6] * inv, O[i][7] * inv);
    }
}

// ---------------------------------------------------------------- router (fp32, top-1 + sigmoid)
__global__ __launch_bounds__(256) void router_kernel(
    const float* __restrict__ t, const float* __restrict__ rw,
    int* __restrict__ topi, float* __restrict__ gate)
{
    const int wid = threadIdx.x >> 6, lane = threadIdx.x & 63;
    const int tok = blockIdx.x * 4 + wid;
    const float* x = t + (size_t)tok * DD;
    float acc[NE] = {};
    for (int d = lane; d < DD; d += 64) {
        const float xv = x[d];
        const float4 r0 = *(const float4*)&rw[d * NE];
        const float4 r1 = *(const float4*)&rw[d * NE + 4];
        acc[0] = fmaf(xv, r0.x, acc[0]); acc[1] = fmaf(xv, r0.y, acc[1]);
        acc[2] = fmaf(xv, r0.z, acc[2]); acc[3] = fmaf(xv, r0.w, acc[3]);
        acc[4] = fmaf(xv, r1.x, acc[4]); acc[5] = fmaf(xv, r1.y, acc[5]);
        acc[6] = fmaf(xv, r1.z, acc[6]); acc[7] = fmaf(xv, r1.w, acc[7]);
    }
#pragma unroll
    for (int e = 0; e < NE; ++e)
        for (int off = 32; off; off >>= 1) acc[e] += __shfl_xor(acc[e], off);
    if (lane == 0) {
        int best = 0;
        float bv = acc[0];
#pragma unroll
        for (int e = 1; e < NE; ++e)
            if (acc[e] > bv) { bv = acc[e]; best = e; }
        topi[tok] = best;
        gate[tok] = 1.0f / (1.0f + __expf(-bv));
    }
}

__global__ void scatter_kernel(const int* __restrict__ topi,
                               int* __restrict__ counts, int* __restrict__ tok_list)
{
    const int t = blockIdx.x * 256 + threadIdx.x;
    const int e = topi[t];
    const int pos = atomicAdd(&counts[e], 1);
    tok_list[e * TT + pos] = t;
}

// pcnt[e] = cnt padded to 128; off[e] = cumsum of pcnt
__global__ void offsets_kernel(const int* __restrict__ counts,
                               int* __restrict__ pcnt, int* __restrict__ off)
{
    if (threadIdx.x == 0 && blockIdx.x == 0) {
        int o = 0;
        for (int e = 0; e < NE; ++e) {
            const int p = ((counts[e] + 127) >> 7) << 7;
            pcnt[e] = p;
            off[e] = o;
            o += p;
        }
    }
}

// gather: Ag[off[e]+i] = tb[tok]*gate[tok] (bf16), zero pad rows; rowmap
__global__ __launch_bounds__(256) void gather_kernel(
    const ushort* __restrict__ tb, const float* __restrict__ gate,
    const int* __restrict__ tok_list, const int* __restrict__ counts,
    const int* __restrict__ pcnt, const int* __restrict__ off,
    ushort* __restrict__ Ag, int* __restrict__ rowmap)
{
    const int e = blockIdx.y;
    const int r = blockIdx.x * 128 + (threadIdx.x >> 1);
    if (r >= pcnt[e]) return;
    const int half = (threadIdx.x & 1) * 1024;
    const int grow = off[e] + r;
    const int cnt = counts[e];
    if (r < cnt) {
        const int tok = tok_list[e * TT + r];
        if ((threadIdx.x & 1) == 0) rowmap[grow] = tok;
        const float g = gate[tok];
        const ushort* src = tb + (size_t)tok * DD + half;
        ushort* dst = Ag + (size_t)grow * DD + half;
        for (int i = 0; i < 1024; i += 8) {
            uint4 u = *(const uint4*)&src[i];
            unsigned int w[4] = {u.x, u.y, u.z, u.w};
            unsigned int o[4];
#pragma unroll
            for (int j = 0; j < 4; ++j) {
                const float lo = bf2f((ushort)(w[j] & 0xffff)) * g;
                const float hi = bf2f((ushort)(w[j] >> 16)) * g;
                o[j] = (unsigned int)f2bf(lo) | ((unsigned int)f2bf(hi) << 16);
            }
            *(uint4*)&dst[i] = make_uint4(o[0], o[1], o[2], o[3]);
        }
    } else {
        if ((threadIdx.x & 1) == 0) rowmap[grow] = -1;
        ushort* dst = Ag + (size_t)grow * DD + half;
        const uint4 z = make_uint4(0, 0, 0, 0);
        for (int i = 0; i < 1024; i += 8) *(uint4*)&dst[i] = z;
    }
}

// ---------------------------------------------------------------- transpose fp32(R,C) -> bf16(C,R)
__global__ __launch_bounds__(256) void transpose_bf16_kernel(
    const float* __restrict__ src, ushort* __restrict__ dst, int R, int C)
{
    __shared__ float t[64][65];
    src += (size_t)blockIdx.z * R * C;
    dst += (size_t)blockIdx.z * R * C;
    const int r0 = blockIdx.y * 64, c0 = blockIdx.x * 64;
    const int lr = threadIdx.x >> 4;
    const int lc = (threadIdx.x & 15) << 2;
#pragma unroll
    for (int i = 0; i < 4; ++i) {
        const float4 v = *(const float4*)&src[(size_t)(r0 + lr + i * 16) * C + c0 + lc];
        t[lr + i * 16][lc + 0] = v.x;
        t[lr + i * 16][lc + 1] = v.y;
        t[lr + i * 16][lc + 2] = v.z;
        t[lr + i * 16][lc + 3] = v.w;
    }
    __syncthreads();
#pragma unroll
    for (int i = 0; i < 4; ++i) {
        const int oc = lr + i * 16;
        ushort4 o;
        o.x = f2bf(t[lc + 0][oc]);
        o.y = f2bf(t[lc + 1][oc]);
        o.z = f2bf(t[lc + 2][oc]);
        o.w = f2bf(t[lc + 3][oc]);
        *(ushort4*)&dst[(size_t)(c0 + oc) * R + r0 + lc] = o;
    }
}

// ---------------------------------------------------------------- bf16 MFMA GEMM (m97-style)
// C[M,N] = A[M,K] @ Bt[N,K]^T. 128x128 tile, BK=64, global_load_lds w=16,
// ADD-swizzled LDS chunks (conflict-free frag reads). modes: 0 fp32, 1 fp32+res, 2 bf16
__global__ __launch_bounds__(256, 2) void gemm_bf16_kernel(
    const ushort* __restrict__ A, const ushort* __restrict__ Bt,
    const float* __restrict__ res, float* __restrict__ Cf, ushort* __restrict__ Cb,
    int M, int N, int K, int mode)
{
    __shared__ ushort As[128 * 64];
    __shared__ ushort Bs[128 * 64];
    const int tid = threadIdx.x;
    const int lane = tid & 63, w = tid >> 6;
    const int wr = (w >> 1) * 64, wc = (w & 1) * 64;
    const int bm = blockIdx.y * 128, bn = blockIdx.x * 128;
    f32x4 acc[4][4] = {};
    const int sr = tid >> 3, cs = tid & 7;
    const int lm = lane & 15, q = lane >> 4;
    for (int k0 = 0; k0 < K; k0 += 64) {
        __syncthreads();
#pragma unroll
        for (int p = 0; p < 4; ++p) {
            const int r = p * 32 + sr;
            const int cg = (cs - r) & 7;
            gload_lds16(A + (size_t)(bm + r) * K + k0 + cg * 8, (char*)As + p * 4096 + tid * 16);
            gload_lds16(Bt + (size_t)(bn + r) * K + k0 + cg * 8, (char*)Bs + p * 4096 + tid * 16);
        }
        __syncthreads();
#pragma unroll
        for (int kk = 0; kk < 64; kk += 32) {
            const int kc = (kk >> 3) + q;
            short8 a[4], b[4];
#pragma unroll
            for (int i = 0; i < 4; ++i) {
                const int mr = wr + i * 16 + lm;
                a[i] = *(const short8*)((const char*)As + mr * 128 + (((kc + mr) & 7) << 4));
                const int nr = wc + i * 16 + lm;
                b[i] = *(const short8*)((const char*)Bs + nr * 128 + (((kc + nr) & 7) << 4));
            }
#pragma unroll
            for (int i = 0; i < 4; ++i)
#pragma unroll
                for (int j = 0; j < 4; ++j)
                    acc[i][j] = __builtin_amdgcn_mfma_f32_16x16x32_bf16(a[i], b[j], acc[i][j], 0, 0, 0);
        }
    }
#pragma unroll
    for (int i = 0; i < 4; ++i) {
#pragma unroll
        for (int rg = 0; rg < 4; ++rg) {
            const int row = bm + wr + i * 16 + q * 4 + rg;
#pragma unroll
            for (int j = 0; j < 4; ++j) {
                const int col = bn + wc + j * 16 + lm;
                const float vv = acc[i][j][rg];
                if (mode == 0) Cf[(size_t)row * N + col] = vv;
                else if (mode == 1) Cf[(size_t)row * N + col] = vv + res[(size_t)row * N + col];
                else Cb[(size_t)row * N + col] = f2bf(vv);
            }
        }
    }
}

// grouped MoE GEMM1: gub[grow] = Ag[grow] @ gupT[e]^T  (N=4096, bf16 out)
__global__ __launch_bounds__(256, 2) void moe_gemm1_bf16_kernel(
    const ushort* __restrict__ Ag, const ushort* __restrict__ gupT,
    const int* __restrict__ pcnt, const int* __restrict__ off,
    ushort* __restrict__ gub)
{
    const int e = blockIdx.z;
    const int row0 = blockIdx.y * 128;
    if (row0 >= pcnt[e]) return;
    const int base = off[e] + row0;
    const ushort* Bt = gupT + (size_t)e * 4096 * 2048;
    const int N = 4096, K = 2048;
    __shared__ ushort As[128 * 64];
    __shared__ ushort Bs[128 * 64];
    const int tid = threadIdx.x;
    const int lane = tid & 63, w = tid >> 6;
    const int wr = (w >> 1) * 64, wc = (w & 1) * 64;
    const int bn = blockIdx.x * 128;
    f32x4 acc[4][4] = {};
    const int sr = tid >> 3, cs = tid & 7;
    const int lm = lane & 15, q = lane >> 4;
    for (int k0 = 0; k0 < K; k0 += 64) {
        __syncthreads();
#pragma unroll
        for (int p = 0; p < 4; ++p) {
            const int r = p * 32 + sr;
            const int cg = (cs - r) & 7;
            gload_lds16(Ag + (size_t)(base + r) * K + k0 + cg * 8, (char*)As + p * 4096 + tid * 16);
            gload_lds16(Bt + (size_t)(bn + r) * K + k0 + cg * 8, (char*)Bs + p * 4096 + tid * 16);
        }
        __syncthreads();
#pragma unroll
        for (int kk = 0; kk < 64; kk += 32) {
            const int kc = (kk >> 3) + q;
            short8 a[4], b[4];
#pragma unroll
            for (int i = 0; i < 4; ++i) {
                const int mr = wr + i * 16 + lm;
                a[i] = *(const short8*)((const char*)As + mr * 128 + (((kc + mr) & 7) << 4));
                const int nr = wc + i * 16 + lm;
                b[i] = *(const short8*)((const char*)Bs + nr * 128 + (((kc + nr) & 7) << 4));
            }
#pragma unroll
            for (int i = 0; i < 4; ++i)
#pragma unroll
                for (int j = 0; j < 4; ++j)
                    acc[i][j] = __builtin_amdgcn_mfma_f32_16x16x32_bf16(a[i], b[j], acc[i][j], 0, 0, 0);
        }
    }
#pragma unroll
    for (int i = 0; i < 4; ++i)
#pragma unroll
        for (int rg = 0; rg < 4; ++rg) {
            const int row = base + wr + i * 16 + q * 4 + rg;
#pragma unroll
            for (int j = 0; j < 4; ++j) {
                const int col = bn + wc + j * 16 + lm;
                gub[(size_t)row * N + col] = f2bf(acc[i][j][rg]);
            }
        }
}

// grouped MoE GEMM2: out[rowmap[grow]] += hmidb[grow] @ dprojT[e]^T  (N=2048)
__global__ __launch_bounds__(256, 2) void moe_gemm2_bf16_kernel(
    const ushort* __restrict__ hmidb, const ushort* __restrict__ dprojT,
    const int* __restrict__ pcnt, const int* __restrict__ off,
    const int* __restrict__ rowmap, float* __restrict__ out)
{
    const int e = blockIdx.z;
    const int row0 = blockIdx.y * 128;
    if (row0 >= pcnt[e]) return;
    const int base = off[e] + row0;
    const ushort* Bt = dprojT + (size_t)e * 2048 * 2048;
    const int N = 2048, K = 2048;
    __shared__ ushort As[128 * 64];
    __shared__ ushort Bs[128 * 64];
    const int tid = threadIdx.x;
    const int lane = tid & 63, w = tid >> 6;
    const int wr = (w >> 1) * 64, wc = (w & 1) * 64;
    const int bn = blockIdx.x * 128;
    f32x4 acc[4][4] = {};
    const int sr = tid >> 3, cs = tid & 7;
    const int lm = lane & 15, q = lane >> 4;
    for (int k0 = 0; k0 < K; k0 += 64) {
        __syncthreads();
#pragma unroll
        for (int p = 0; p < 4; ++p) {
            const int r = p * 32 + sr;
            const int cg = (cs - r) & 7;
            gload_lds16(hmidb + (size_t)(base + r) * K + k0 + cg * 8, (char*)As + p * 4096 + tid * 16);
            gload_lds16(Bt + (size_t)(bn + r) * K + k0 + cg * 8, (char*)Bs + p * 4096 + tid * 16);
        }
        __syncthreads();
#pragma unroll
        for (int kk = 0; kk < 64; kk += 32) {
            const int kc = (kk >> 3) + q;
            short8 a[4], b[4];
#pragma unroll
            for (int i = 0; i < 4; ++i) {
                const int mr = wr + i * 16 + lm;
                a[i] = *(const short8*)((const char*)As + mr * 128 + (((kc + mr) & 7) << 4));
                const int nr = wc + i * 16 + lm;
                b[i] = *(const short8*)((const char*)Bs + nr * 128 + (((kc + nr) & 7) << 4));
            }
#pragma unroll
            for (int i = 0; i < 4; ++i)
#pragma unroll
                for (int j = 0; j < 4; ++j)
                    acc[i][j] = __builtin_amdgcn_mfma_f32_16x16x32_bf16(a[i], b[j], acc[i][j], 0, 0, 0);
        }
    }
#pragma unroll
    for (int i = 0; i < 4; ++i)
#pragma unroll
        for (int rg = 0; rg < 4; ++rg) {
            const int grow = base + wr + i * 16 + q * 4 + rg;
            const int tok = rowmap[grow];
            if (tok < 0) continue;
#pragma unroll
            for (int j = 0; j < 4; ++j) {
                const int col = bn + wc + j * 16 + lm;
                out[(size_t)tok * N + col] += acc[i][j][rg];
            }
        }
}

// ---------------------------------------------------------------- elementwise acts
// smid fp32 (T,4096) -> smidb bf16 (T,2048): up*silu(gate)
__global__ void silu_mul_b_kernel(const float* __restrict__ smid, ushort* __restrict__ smidb)
{
    const size_t i = (size_t)blockIdx.x * 256 + threadIdx.x;
    const size_t t = i >> 11;
    const size_t f = i & (FF - 1);
    const float g = smid[t * 4096 + f];
    const float u = smid[t * 4096 + 2048 + f];
    smidb[i] = f2bf(u * (g / (1.0f + __expf(-g))));
}

// gub bf16 (rows,4096) -> hmidb bf16 (rows,2048)
__global__ void gu_act_b_kernel(const ushort* __restrict__ gub, ushort* __restrict__ hmidb)
{
    const size_t i = (size_t)blockIdx.x * 256 + threadIdx.x;
    const size_t t = i >> 11;
    const size_t f = i & (FF - 1);
    const float g = bf2f(gub[t * 4096 + f]);
    const float u = bf2f(gub[t * 4096 + 2048 + f]);
    hmidb[i] = f2bf(u * (g / (1.0f + __expf(-g))));
}

// ---------------------------------------------------------------- launch
extern "C" void kernel_launch(void* const* d_in, const int* in_sizes, int n_in,
                              void* d_out, int out_size, void* d_ws, size_t ws_size,
                              hipStream_t stream)
{
    const float* hidden = (const float*)d_in[0];
    const float* fcos   = (const float*)d_in[1];
    const float* fsin   = (const float*)d_in[2];
    const float* wq     = (const float*)d_in[5];
    const float* wk     = (const float*)d_in[6];
    const float* wv     = (const float*)d_in[7];
    const float* wo     = (const float*)d_in[8];
    const float* ln1    = (const float*)d_in[9];
    const float* ln2    = (const float*)d_in[10];
    const float* rw     = (const float*)d_in[11];
    const float* gup    = (const float*)d_in[12];
    const float* dproj  = (const float*)d_in[13];
    const float* sgw    = (const float*)d_in[14];
    const float* suw    = (const float*)d_in[15];
    const float* sdw    = (const float*)d_in[16];
    float* out = (float*)d_out;

    float* wsf = (float*)d_ws;
    const size_t M1 = 1024 * 1024;
    // fp32 stage buffers (attn path)
    float* hsn  = wsf;              // [0,4M)  rms1 out; later Ag overlays [0,3M)
    float* qb   = wsf + 4 * M1;     // [4,8)
    float* kb   = wsf + 8 * M1;     // [8,9)
    float* vb   = wsf + 9 * M1;     // [9,10)
    float* ab   = wsf + 10 * M1;    // [10,14)
    float* hs2  = wsf + 14 * M1;    // [14,18)
    float* t32  = wsf + 18 * M1;    // [18,22) rms2 fp32 (router); later smidb overlays [18,20)
    float* smid = wsf + 4 * M1;     // [4,12)  fp32 shared gate|up (q/k/v dead by then)
    // bf16 buffers
    ushort* xb     = (ushort*)(wsf + 12 * M1);  // [12,14) t bf16 (ab dead when written)
    ushort* smidb  = (ushort*)(wsf + 18 * M1);  // [18,20)
    ushort* Ag     = (ushort*)(wsf + 0);        // [0,3)   gathered routed input (3072 rows)
    ushort* gub    = (ushort*)(wsf + 22 * M1);  // [22,28) (3072,4096)
    ushort* hmidb  = (ushort*)(wsf + 28 * M1);  // [28,31) (3072,2048)
    // bf16 transposed weights
    ushort* ssT    = (ushort*)(wsf + 31 * M1);  // [31,35) (4096,2048)
    ushort* sdwT   = (ushort*)(wsf + 35 * M1);  // [35,37) (2048,2048)
    ushort* gupT   = (ushort*)(wsf + 37 * M1);  // [37,69) (8,4096,2048)
    ushort* dprojT = (ushort*)(wsf + 69 * M1);  // [69,85) (8,2048,2048)
    // small int/float buffers
    float* ibase    = wsf + 85 * M1;
    int*   topi     = (int*)ibase;
    float* gate     = ibase + 2048;
    int*   counts   = (int*)(ibase + 4096);
    int*   tok_list = (int*)(ibase + 4096 + 64);
    int*   pcnt     = (int*)(ibase + 4096 + 64 + NE * TT);
    int*   off      = pcnt + 8;
    int*   rowmap   = off + 8;

    hipMemsetAsync(counts, 0, NE * sizeof(int), stream);

    // weight transposes (fp32 -> bf16 N x K), independent of data flow
    transpose_bf16_kernel<<<dim3(32, 32, 1), 256, 0, stream>>>(sgw, ssT, 2048, 2048);
    transpose_bf16_kernel<<<dim3(32, 32, 1), 256, 0, stream>>>(suw, ssT + (size_t)2048 * 2048, 2048, 2048);
    transpose_bf16_kernel<<<dim3(32, 32, 1), 256, 0, stream>>>(sdw, sdwT, 2048, 2048);
    transpose_bf16_kernel<<<dim3(64, 32, 8), 256, 0, stream>>>(gup, gupT, 2048, 4096);
    transpose_bf16_kernel<<<dim3(32, 32, 8), 256, 0, stream>>>(dproj, dprojT, 2048, 2048);

    // attn block (fp32 — protects router top-1 from precision flips)
    rmsnorm_kernel<<<TT, 256, 0, stream>>>(hidden, ln1, hsn);
    gemm_f32_kernel<<<dim3(2048 / TILE, TT / TILE), 256, 0, stream>>>(hsn, wq, qb, nullptr, TT, 2048, DD);
    gemm_f32_kernel<<<dim3(512 / TILE, TT / TILE), 256, 0, stream>>>(hsn, wk, kb, nullptr, TT, 512, DD);
    gemm_f32_kernel<<<dim3(512 / TILE, TT / TILE), 256, 0, stream>>>(hsn, wv, vb, nullptr, TT, 512, DD);
    rope_l2_kernel<<<TT * NHQ / 4, 256, 0, stream>>>(qb, NHQ, fcos, fsin);
    rope_l2_kernel<<<TT * KVH / 4, 256, 0, stream>>>(kb, KVH, fcos, fsin);
    attn_flash_kernel<<<512, 256, 0, stream>>>(qb, kb, vb, ab);
    gemm_f32_kernel<<<dim3(DD / TILE, TT / TILE), 256, 0, stream>>>(ab, wo, hs2, hidden, TT, DD, 2048);

    // moe block
    rmsnorm_dual_kernel<<<TT, 256, 0, stream>>>(hs2, ln2, t32, xb);
    router_kernel<<<TT / 4, 256, 0, stream>>>(t32, rw, topi, gate);
    scatter_kernel<<<TT / 256, 256, 0, stream>>>(topi, counts, tok_list);
    offsets_kernel<<<1, 64, 0, stream>>>(counts, pcnt, off);
    gather_kernel<<<dim3(16, 8), 256, 0, stream>>>(xb, gate, tok_list, counts, pcnt, off, Ag, rowmap);

    // shared FFN: [gate|up] fused N=4096 (bf16 MFMA)
    gemm_bf16_kernel<<<dim3(32, 16), 256, 0, stream>>>(xb, ssT, nullptr, smid, nullptr, TT, 4096, DD, 0);
    silu_mul_b_kernel<<<TT * FF / 256, 256, 0, stream>>>(smid, smidb);
    // routed expert FFN (bf16 MFMA, grouped over padded segments)
    moe_gemm1_bf16_kernel<<<dim3(32, 16, 8), 256, 0, stream>>>(Ag, gupT, pcnt, off, gub);
    gu_act_b_kernel<<<3072 * FF / 256, 256, 0, stream>>>(gub, hmidb);
    // out = hs2 + shared_down (bf16 MFMA + residual)
    gemm_bf16_kernel<<<dim3(16, 16), 256, 0, stream>>>(smidb, sdwT, hs2, out, nullptr, TT, DD, FF, 1);
    // out += routed (scatter-add epilogue)
    moe_gemm2_bf16_kernel<<<dim3(16, 16, 8), 256, 0, stream>>>(hmidb, dprojT, pcnt, off, rowmap, out);
}